// Round 18
// baseline (824.331 us; speedup 1.0000x reference)
//
#include <hip/hip_runtime.h>

#define NHW 9216
#define NCH 256
#define SCALE 0.0625f

typedef __attribute__((ext_vector_type(8))) short bfrag;          // 8 bf16
typedef __attribute__((ext_vector_type(4))) float f32x4;          // MFMA C/D
typedef __attribute__((ext_vector_type(8))) unsigned short u16x8;
typedef __attribute__((address_space(3))) unsigned as3_u32;
typedef const __attribute__((address_space(1))) unsigned as1_u32;

__device__ __forceinline__ unsigned short f2bf(float x) {  // RNE f32->bf16
    unsigned u = __builtin_bit_cast(unsigned, x);
    u += 0x7FFFu + ((u >> 16) & 1u);
    return (unsigned short)(u >> 16);
}

#define MFMA(a, b, c) __builtin_amdgcn_mfma_f32_16x16x32_bf16((a), (b), (c), 0, 0, 0)

// ---------------------------------------------------------------------------
// LDS-tiled transpose+convert: src [256 c][9216 n] f32 -> dst [9216 n][256 c] bf16
// ---------------------------------------------------------------------------
__global__ __launch_bounds__(256) void k_prep(const float* __restrict__ fm,
                                              const float* __restrict__ ft,
                                              unsigned short* __restrict__ fmT,
                                              unsigned short* __restrict__ ftT) {
    __shared__ float smT[64][257];
    const float* src = blockIdx.y ? ft : fm;
    unsigned short* dst = blockIdx.y ? ftT : fmT;
    const int t = threadIdx.x;
    const int n0 = blockIdx.x * 64;
    {
        const int n = t & 63;
        const int cb = t >> 6;
        for (int p = 0; p < 64; ++p) {
            const int c = p * 4 + cb;
            smT[n][c] = src[(size_t)c * NHW + n0 + n];
        }
    }
    __syncthreads();
    {
        const int n = t >> 2;
        const int c0 = (t & 3) * 64;
#pragma unroll
        for (int cc = 0; cc < 64; cc += 8) {
            const float4 v0 = *(const float4*)(&smT[n][c0 + cc]);
            const float4 v1 = *(const float4*)(&smT[n][c0 + cc + 4]);
            u16x8 o;
            o[0] = f2bf(v0.x); o[1] = f2bf(v0.y); o[2] = f2bf(v0.z); o[3] = f2bf(v0.w);
            o[4] = f2bf(v1.x); o[5] = f2bf(v1.y); o[6] = f2bf(v1.z); o[7] = f2bf(v1.w);
            *(u16x8*)(dst + (size_t)(n0 + n) * NCH + c0 + cc) = o;
        }
    }
}

__global__ __launch_bounds__(256) void k_prepw(const float* __restrict__ tw,
                                               unsigned short* __restrict__ twb) {
    const int i = blockIdx.x * 256 + threadIdx.x;
    twb[i] = f2bf(tw[i]);
}

// ---------------------------------------------------------------------------
// k_se (m97-style): Zpart[slice][n] partial sums + E store (frag-ready).
// grid flat 1152: by = id&15 (m-split 576), bx = id>>4 (n-tile 128).
// ---------------------------------------------------------------------------
__global__ __launch_bounds__(256, 2) void k_se(const unsigned short* __restrict__ fmT,
                                               const unsigned short* __restrict__ ftT,
                                               float* __restrict__ Zpart,
                                               unsigned short* __restrict__ E,
                                               int storeE) {
    __shared__ unsigned short smB[2][16384];  // 2 x 32 KB
    const int t = threadIdx.x;
    const int w = t >> 6, l = t & 63;
    const int lr = l & 15, lk = l >> 4;
    const int id = blockIdx.x;
    const int by = id & 15;
    const int bx = id >> 4;
    const int n0 = bx * 128 + w * 32;
    const int mb = by * 576;

    bfrag a[2][8];
#pragma unroll
    for (int i = 0; i < 2; ++i)
#pragma unroll
        for (int ks = 0; ks < 8; ++ks)
            a[i][ks] = *(const bfrag*)(fmT + (size_t)(n0 + i * 16 + lr) * NCH + ks * 32 + lk * 8);

    float zacc[2][4] = {};
    f32x4 accA[2][4], accB[2][4];

#define STAGE(buf, mt)                                                                   \
    {                                                                                    \
        const int sm0 = mb + (mt) * 64;                                                  \
        _Pragma("unroll") for (int p = 0; p < 8; ++p) {                                  \
            const int chunkb = p * 256 + w * 64;                                         \
            const int chunk = chunkb + l;                                                \
            const int m = chunk >> 5;                                                    \
            const int scb = (chunk & 31) ^ (m & 7);                                      \
            const unsigned short* gp = ftT + (size_t)(sm0 + m) * NCH + scb * 8;          \
            unsigned short* lp = &smB[buf][0] + (size_t)chunk * 8;                       \
            __builtin_amdgcn_global_load_lds((as1_u32*)gp, (as3_u32*)lp, 16, 0, 0);      \
        }                                                                                \
    }

#define COMPUTE(acc, buf)                                                                \
    {                                                                                    \
        _Pragma("unroll") for (int i = 0; i < 2; ++i)                                    \
            _Pragma("unroll") for (int j = 0; j < 4; ++j) acc[i][j] = (f32x4){0,0,0,0};  \
        _Pragma("unroll") for (int ks = 0; ks < 8; ++ks) {                               \
            bfrag b[4];                                                                  \
            _Pragma("unroll") for (int j = 0; j < 4; ++j) {                              \
                const int mloc = j * 16 + lr;                                            \
                const int cb = ks * 4 + lk;                                              \
                b[j] = *(const bfrag*)(&smB[buf][mloc * 256 + ((cb ^ (mloc & 7)) << 3)]);\
            }                                                                            \
            _Pragma("unroll") for (int i = 0; i < 2; ++i)                                \
                _Pragma("unroll") for (int j = 0; j < 4; ++j)                            \
                    acc[i][j] = MFMA(a[i][ks], b[j], acc[i][j]);                         \
        }                                                                                \
    }

#define EXPSTORE(acc, mt)                                                                \
    {                                                                                    \
        const int sm0 = mb + (mt) * 64;                                                  \
        _Pragma("unroll") for (int i = 0; i < 2; ++i) {                                  \
            const int grp = (n0 + i * 16 + lk * 4) >> 3;                                 \
            const int sub = (lk & 1) * 4;                                                \
            _Pragma("unroll") for (int j = 0; j < 4; ++j) {                              \
                float e0 = __expf(acc[i][j][0] * SCALE);                                 \
                float e1 = __expf(acc[i][j][1] * SCALE);                                 \
                float e2 = __expf(acc[i][j][2] * SCALE);                                 \
                float e3 = __expf(acc[i][j][3] * SCALE);                                 \
                zacc[i][0] += e0; zacc[i][1] += e1;                                      \
                zacc[i][2] += e2; zacc[i][3] += e3;                                      \
                if (storeE) {                                                            \
                    const int m = sm0 + j * 16 + lr;                                     \
                    uint2 v;                                                             \
                    v.x = (unsigned)f2bf(e0) | ((unsigned)f2bf(e1) << 16);               \
                    v.y = (unsigned)f2bf(e2) | ((unsigned)f2bf(e3) << 16);               \
                    *(uint2*)(&E[((size_t)grp * NHW + m) * 8 + sub]) = v;                \
                }                                                                        \
            }                                                                            \
        }                                                                                \
    }

    STAGE(0, 0)
    __syncthreads();
    STAGE(1, 1)
    COMPUTE(accA, 0)    // mt 0
    __syncthreads();
    for (int base = 1; base + 1 < 9; base += 2) {
        STAGE(0, base + 1)
        EXPSTORE(accA, base - 1)
        COMPUTE(accB, 1)        // mt = base (odd, buf 1)
        __syncthreads();
        if (base + 2 < 9) STAGE(1, base + 2)
        EXPSTORE(accB, base)
        COMPUTE(accA, 0)        // mt = base+1 (even, buf 0)
        __syncthreads();
    }
    EXPSTORE(accA, 8)
#undef STAGE
#undef COMPUTE
#undef EXPSTORE

#pragma unroll
    for (int i = 0; i < 2; ++i)
#pragma unroll
        for (int r = 0; r < 4; ++r) {
            float v = zacc[i][r];
            v += __shfl_xor(v, 1);
            v += __shfl_xor(v, 2);
            v += __shfl_xor(v, 4);
            v += __shfl_xor(v, 8);
            if (lr == 0) Zpart[(size_t)by * NHW + n0 + i * 16 + lk * 4 + r] = v;
        }
}

// ---------------------------------------------------------------------------
// Merged k_g / k_base.  z=0: G' = (W1@fm)/Z in A-frag-ready layout
// G'[(n>>3)*2048 + o*8 + (n&7)]; z=1: out = W2@ft + b.
// ---------------------------------------------------------------------------
__global__ __launch_bounds__(256) void k_gb(const unsigned short* __restrict__ twb,
                                            const unsigned short* __restrict__ fmT,
                                            const unsigned short* __restrict__ ftT,
                                            const float* __restrict__ Zpart,
                                            const float* __restrict__ tb,
                                            unsigned short* __restrict__ G,
                                            float* __restrict__ out) {
    const int tid = threadIdx.x;
    const int w = tid >> 6, l = tid & 63;
    const int wo = w >> 1, wm = w & 1;
    const int lr = l & 15, lk = l >> 4;
    const int mode = blockIdx.z;
    const int n0 = blockIdx.x * 128, o0 = blockIdx.y * 128;
    const unsigned short* B = mode ? ftT : fmT;
    const int wofs = mode ? 256 : 0;
    f32x4 acc[4][4] = {};
#pragma unroll
    for (int ks = 0; ks < 8; ++ks) {
        const int k = ks * 32 + lk * 8;
        bfrag a[4], b[4];
#pragma unroll
        for (int i = 0; i < 4; ++i)
            a[i] = *(const bfrag*)(twb + (size_t)(o0 + wo * 64 + i * 16 + lr) * 512 + wofs + k);
#pragma unroll
        for (int j = 0; j < 4; ++j)
            b[j] = *(const bfrag*)(B + (size_t)(n0 + wm * 64 + j * 16 + lr) * NCH + k);
#pragma unroll
        for (int i = 0; i < 4; ++i)
#pragma unroll
            for (int j = 0; j < 4; ++j) acc[i][j] = MFMA(a[i], b[j], acc[i][j]);
    }
    if (mode == 0) {
        float zi[4];
#pragma unroll
        for (int j = 0; j < 4; ++j) {
            const int n = n0 + wm * 64 + j * 16 + lr;
            float z = 0.f;
#pragma unroll
            for (int s = 0; s < 16; ++s) z += Zpart[(size_t)s * NHW + n];
            zi[j] = 1.f / z;
        }
#pragma unroll
        for (int i = 0; i < 4; ++i)
#pragma unroll
            for (int j = 0; j < 4; ++j)
#pragma unroll
                for (int r = 0; r < 4; ++r) {
                    const int o = o0 + wo * 64 + i * 16 + lk * 4 + r;
                    const int n = n0 + wm * 64 + j * 16 + lr;
                    G[(size_t)(n >> 3) * 2048 + o * 8 + (n & 7)] = f2bf(acc[i][j][r] * zi[j]);
                }
    } else {
#pragma unroll
        for (int i = 0; i < 4; ++i)
#pragma unroll
            for (int j = 0; j < 4; ++j)
#pragma unroll
                for (int r = 0; r < 4; ++r) {
                    const int o = o0 + wo * 64 + i * 16 + lk * 4 + r;
                    const int m = n0 + wm * 64 + j * 16 + lr;
                    out[(size_t)o * NHW + m] = acc[i][j][r] + tb[o];
                }
    }
}

// ---------------------------------------------------------------------------
// k_apply v10: r15 dataflow, 1-WAVE BLOCKS for occupancy. The kernel is
// barrier-free, so the 4 o-strip waves need not share a block; at VGPR=84 a
// 64-thread block lets the scheduler pack up to 6 waves/SIMD (24 waves/CU,
// 3x the 256-thread version's 8). grid flat 4608: by = id&7 (n-split ==
// XCD), w = (id>>3)&3 (o-strip; adjacent ids share eb stream -> L1/L2
// temporal locality), bx = id>>5 (m-tile 64).
// ---------------------------------------------------------------------------
__global__ __launch_bounds__(64, 5) void k_apply(const unsigned short* __restrict__ G,
                                                 const unsigned short* __restrict__ E,
                                                 float* __restrict__ out) {
    const int l = threadIdx.x;
    const int lr = l & 15, lk = l >> 4;
    const int id = blockIdx.x;
    const int by = id & 7;
    const int rem = id >> 3;
    const int w = rem & 3;
    const int bx = rem >> 2;
    const int m0 = bx * 64;
    const int gbase = by * 144;  // (by*1152)>>3

    f32x4 U[4][4] = {};
    bfrag gaA[4], ebA[4], gaB[4], ebB[4];

#define LOADSET(ga, eb, s)                                                                        \
    {                                                                                             \
        _Pragma("unroll") for (int i = 0; i < 4; ++i)                                             \
            ga[i] = *(const bfrag*)(&G[(size_t)(gbase + (s) * 4 + lk) * 2048 +                    \
                                       (w * 64 + i * 16 + lr) * 8]);                              \
        _Pragma("unroll") for (int j = 0; j < 4; ++j)                                             \
            eb[j] = *(const bfrag*)(&E[((size_t)(gbase + (s) * 4 + lk) * NHW + m0 + j * 16 + lr) * 8]); \
    }
#define MFMASET(ga, eb)                                                                           \
    {                                                                                             \
        __builtin_amdgcn_s_setprio(1);                                                            \
        _Pragma("unroll") for (int i = 0; i < 4; ++i)                                             \
            _Pragma("unroll") for (int j = 0; j < 4; ++j) U[i][j] = MFMA(ga[i], eb[j], U[i][j]);  \
        __builtin_amdgcn_s_setprio(0);                                                            \
    }

    LOADSET(gaA, ebA, 0)
#pragma unroll 2
    for (int s = 0; s < 36; s += 2) {
        LOADSET(gaB, ebB, s + 1)
        MFMASET(gaA, ebA)
        if (s + 2 < 36) LOADSET(gaA, ebA, s + 2)
        MFMASET(gaB, ebB)
    }
#undef LOADSET
#undef MFMASET

#pragma unroll
    for (int i = 0; i < 4; ++i)
#pragma unroll
        for (int j = 0; j < 4; ++j)
#pragma unroll
            for (int r = 0; r < 4; ++r) {
                const int o = w * 64 + i * 16 + lk * 4 + r;
                const int m = m0 + j * 16 + lr;
                atomicAdd(out + (size_t)o * NHW + m, U[i][j][r]);
            }
}

// ---------------------------------------------------------------------------
// Fallback (ws too small for E): r6 k_main — recomputes S. Uses frag-ready G'.
// ---------------------------------------------------------------------------
__global__ __launch_bounds__(256, 2) void k_main(const unsigned short* __restrict__ fmT,
                                                 const unsigned short* __restrict__ ftT,
                                                 const unsigned short* __restrict__ G,
                                                 float* __restrict__ out) {
    __shared__ unsigned short smB[32 * 64 * 8];
    __shared__ unsigned short smE[48 * 64 * 8];
    const int t = threadIdx.x;
    const int w = t >> 6, l = t & 63;
    const int lr = l & 15, lk = l >> 4;
    const int id = blockIdx.x;
    const int by = id & 7;
    const int bx = id >> 3;
    const int m0 = bx * 64;
    const int nbase = by * 1152;

    {
        const int m = t >> 2;
        const int kc0 = t & 3;
#pragma unroll
        for (int p = 0; p < 8; ++p) {
            const int kc = p * 4 + kc0;
            *(bfrag*)(&smB[(kc * 64 + m) * 8]) =
                *(const bfrag*)(ftT + (size_t)(m0 + m) * NCH + kc * 8);
        }
    }
    __syncthreads();

    f32x4 U[4][4] = {};
    for (int c = 0; c < 3; ++c) {
        const int n0 = nbase + c * 384;
        f32x4 acc[6][4] = {};
#pragma unroll
        for (int ks = 0; ks < 8; ++ks) {
            const int k = ks * 32 + lk * 8;
            bfrag a[6], b[4];
#pragma unroll
            for (int i = 0; i < 6; ++i)
                a[i] = *(const bfrag*)(fmT + (size_t)(n0 + w * 96 + i * 16 + lr) * NCH + k);
#pragma unroll
            for (int j = 0; j < 4; ++j)
                b[j] = *(const bfrag*)(&smB[((ks * 4 + lk) * 64 + j * 16 + lr) * 8]);
#pragma unroll
            for (int i = 0; i < 6; ++i)
#pragma unroll
                for (int j = 0; j < 4; ++j) acc[i][j] = MFMA(a[i], b[j], acc[i][j]);
        }
#pragma unroll
        for (int i = 0; i < 6; ++i)
#pragma unroll
            for (int j = 0; j < 4; ++j) {
                const int m = j * 16 + lr;
                const int grp = w * 12 + i * 2 + (lk >> 1);
                uint2 v;
                v.x = (unsigned)f2bf(__expf(acc[i][j][0] * SCALE)) |
                      ((unsigned)f2bf(__expf(acc[i][j][1] * SCALE)) << 16);
                v.y = (unsigned)f2bf(__expf(acc[i][j][2] * SCALE)) |
                      ((unsigned)f2bf(__expf(acc[i][j][3] * SCALE)) << 16);
                *(uint2*)(&smE[(grp * 64 + m) * 8 + (lk & 1) * 4]) = v;
            }
        __syncthreads();
#pragma unroll
        for (int s = 0; s < 12; ++s) {
            bfrag ga[4], eb[4];
#pragma unroll
            for (int i = 0; i < 4; ++i)
                ga[i] = *(const bfrag*)(&G[(size_t)((n0 + s * 32 + lk * 8) >> 3) * 2048 +
                                           (w * 64 + i * 16 + lr) * 8]);
#pragma unroll
            for (int j = 0; j < 4; ++j)
                eb[j] = *(const bfrag*)(&smE[((s * 4 + lk) * 64 + j * 16 + lr) * 8]);
#pragma unroll
            for (int i = 0; i < 4; ++i)
#pragma unroll
                for (int j = 0; j < 4; ++j) U[i][j] = MFMA(ga[i], eb[j], U[i][j]);
        }
        __syncthreads();
    }
#pragma unroll
    for (int i = 0; i < 4; ++i)
#pragma unroll
        for (int j = 0; j < 4; ++j)
#pragma unroll
            for (int r = 0; r < 4; ++r) {
                const int o = w * 64 + i * 16 + lk * 4 + r;
                const int m = m0 + j * 16 + lr;
                atomicAdd(out + (size_t)o * NHW + m, U[i][j][r]);
            }
}

extern "C" void kernel_launch(void* const* d_in, const int* in_sizes, int n_in,
                              void* d_out, int out_size, void* d_ws, size_t ws_size,
                              hipStream_t stream) {
    const float* fm = (const float*)d_in[0];
    const float* ft = (const float*)d_in[1];
    const float* tw = (const float*)d_in[2];
    const float* tb = (const float*)d_in[3];
    float* out = (float*)d_out;

    char* ws = (char*)d_ws;
    float* Zpart = (float*)ws;                                 // 16*9216*4  = 589824
    unsigned short* twb = (unsigned short*)(ws + 589824);      // 256*512*2  = 262144
    unsigned short* fmT = (unsigned short*)(ws + 851968);      // 9216*256*2 = 4718592
    unsigned short* ftT = (unsigned short*)(ws + 5570560);
    unsigned short* G   = (unsigned short*)(ws + 10289152);    // base = 15007744
    unsigned short* E   = (unsigned short*)(ws + 15007744);    // 9216*9216*2
    const size_t needE = 15007744ull + (size_t)NHW * NHW * 2ull;
    const int useE = (ws_size >= needE) ? 1 : 0;

    k_prep<<<dim3(144, 2), 256, 0, stream>>>(fm, ft, fmT, ftT);
    k_prepw<<<dim3(512), 256, 0, stream>>>(tw, twb);
    k_se<<<dim3(1152), 256, 0, stream>>>(fmT, ftT, Zpart, E, useE);
    k_gb<<<dim3(72, 2, 2), 256, 0, stream>>>(twb, fmT, ftT, Zpart, tb, G, out);
    if (useE)
        k_apply<<<dim3(4608), 64, 0, stream>>>(G, E, out);
    else
        k_main<<<dim3(1152), 256, 0, stream>>>(fmT, ftT, G, out);
}

// Round 19
// 189.624 us; speedup vs baseline: 4.3472x; 4.3472x over previous
//
#include <hip/hip_runtime.h>

#define NHW 9216
#define NCH 256
#define SCALE 0.0625f

typedef __attribute__((ext_vector_type(8))) short bfrag;          // 8 bf16
typedef __attribute__((ext_vector_type(4))) float f32x4;          // MFMA C/D
typedef __attribute__((ext_vector_type(8))) unsigned short u16x8;
typedef __attribute__((address_space(3))) unsigned as3_u32;
typedef const __attribute__((address_space(1))) unsigned as1_u32;

__device__ __forceinline__ unsigned short f2bf(float x) {  // RNE f32->bf16
    unsigned u = __builtin_bit_cast(unsigned, x);
    u += 0x7FFFu + ((u >> 16) & 1u);
    return (unsigned short)(u >> 16);
}

#define MFMA(a, b, c) __builtin_amdgcn_mfma_f32_16x16x32_bf16((a), (b), (c), 0, 0, 0)

// ---------------------------------------------------------------------------
// LDS-tiled transpose+convert: src [256 c][9216 n] f32 -> dst [9216 n][256 c] bf16
// ---------------------------------------------------------------------------
__global__ __launch_bounds__(256) void k_prep(const float* __restrict__ fm,
                                              const float* __restrict__ ft,
                                              unsigned short* __restrict__ fmT,
                                              unsigned short* __restrict__ ftT) {
    __shared__ float smT[64][257];
    const float* src = blockIdx.y ? ft : fm;
    unsigned short* dst = blockIdx.y ? ftT : fmT;
    const int t = threadIdx.x;
    const int n0 = blockIdx.x * 64;
    {
        const int n = t & 63;
        const int cb = t >> 6;
        for (int p = 0; p < 64; ++p) {
            const int c = p * 4 + cb;
            smT[n][c] = src[(size_t)c * NHW + n0 + n];
        }
    }
    __syncthreads();
    {
        const int n = t >> 2;
        const int c0 = (t & 3) * 64;
#pragma unroll
        for (int cc = 0; cc < 64; cc += 8) {
            const float4 v0 = *(const float4*)(&smT[n][c0 + cc]);
            const float4 v1 = *(const float4*)(&smT[n][c0 + cc + 4]);
            u16x8 o;
            o[0] = f2bf(v0.x); o[1] = f2bf(v0.y); o[2] = f2bf(v0.z); o[3] = f2bf(v0.w);
            o[4] = f2bf(v1.x); o[5] = f2bf(v1.y); o[6] = f2bf(v1.z); o[7] = f2bf(v1.w);
            *(u16x8*)(dst + (size_t)(n0 + n) * NCH + c0 + cc) = o;
        }
    }
}

__global__ __launch_bounds__(256) void k_prepw(const float* __restrict__ tw,
                                               unsigned short* __restrict__ twb) {
    const int i = blockIdx.x * 256 + threadIdx.x;
    twb[i] = f2bf(tw[i]);
}

// ---------------------------------------------------------------------------
// k_se (m97-style): Zpart[slice][n] partial sums + E store (frag-ready).
// grid flat 1152: by = id&15 (m-split 576), bx = id>>4 (n-tile 128).
// ---------------------------------------------------------------------------
__global__ __launch_bounds__(256, 2) void k_se(const unsigned short* __restrict__ fmT,
                                               const unsigned short* __restrict__ ftT,
                                               float* __restrict__ Zpart,
                                               unsigned short* __restrict__ E,
                                               int storeE) {
    __shared__ unsigned short smB[2][16384];  // 2 x 32 KB
    const int t = threadIdx.x;
    const int w = t >> 6, l = t & 63;
    const int lr = l & 15, lk = l >> 4;
    const int id = blockIdx.x;
    const int by = id & 15;
    const int bx = id >> 4;
    const int n0 = bx * 128 + w * 32;
    const int mb = by * 576;

    bfrag a[2][8];
#pragma unroll
    for (int i = 0; i < 2; ++i)
#pragma unroll
        for (int ks = 0; ks < 8; ++ks)
            a[i][ks] = *(const bfrag*)(fmT + (size_t)(n0 + i * 16 + lr) * NCH + ks * 32 + lk * 8);

    float zacc[2][4] = {};
    f32x4 accA[2][4], accB[2][4];

#define STAGE(buf, mt)                                                                   \
    {                                                                                    \
        const int sm0 = mb + (mt) * 64;                                                  \
        _Pragma("unroll") for (int p = 0; p < 8; ++p) {                                  \
            const int chunkb = p * 256 + w * 64;                                         \
            const int chunk = chunkb + l;                                                \
            const int m = chunk >> 5;                                                    \
            const int scb = (chunk & 31) ^ (m & 7);                                      \
            const unsigned short* gp = ftT + (size_t)(sm0 + m) * NCH + scb * 8;          \
            unsigned short* lp = &smB[buf][0] + (size_t)chunk * 8;                       \
            __builtin_amdgcn_global_load_lds((as1_u32*)gp, (as3_u32*)lp, 16, 0, 0);      \
        }                                                                                \
    }

#define COMPUTE(acc, buf)                                                                \
    {                                                                                    \
        _Pragma("unroll") for (int i = 0; i < 2; ++i)                                    \
            _Pragma("unroll") for (int j = 0; j < 4; ++j) acc[i][j] = (f32x4){0,0,0,0};  \
        _Pragma("unroll") for (int ks = 0; ks < 8; ++ks) {                               \
            bfrag b[4];                                                                  \
            _Pragma("unroll") for (int j = 0; j < 4; ++j) {                              \
                const int mloc = j * 16 + lr;                                            \
                const int cb = ks * 4 + lk;                                              \
                b[j] = *(const bfrag*)(&smB[buf][mloc * 256 + ((cb ^ (mloc & 7)) << 3)]);\
            }                                                                            \
            _Pragma("unroll") for (int i = 0; i < 2; ++i)                                \
                _Pragma("unroll") for (int j = 0; j < 4; ++j)                            \
                    acc[i][j] = MFMA(a[i][ks], b[j], acc[i][j]);                         \
        }                                                                                \
    }

#define EXPSTORE(acc, mt)                                                                \
    {                                                                                    \
        const int sm0 = mb + (mt) * 64;                                                  \
        _Pragma("unroll") for (int i = 0; i < 2; ++i) {                                  \
            const int grp = (n0 + i * 16 + lk * 4) >> 3;                                 \
            const int sub = (lk & 1) * 4;                                                \
            _Pragma("unroll") for (int j = 0; j < 4; ++j) {                              \
                float e0 = __expf(acc[i][j][0] * SCALE);                                 \
                float e1 = __expf(acc[i][j][1] * SCALE);                                 \
                float e2 = __expf(acc[i][j][2] * SCALE);                                 \
                float e3 = __expf(acc[i][j][3] * SCALE);                                 \
                zacc[i][0] += e0; zacc[i][1] += e1;                                      \
                zacc[i][2] += e2; zacc[i][3] += e3;                                      \
                if (storeE) {                                                            \
                    const int m = sm0 + j * 16 + lr;                                     \
                    uint2 v;                                                             \
                    v.x = (unsigned)f2bf(e0) | ((unsigned)f2bf(e1) << 16);               \
                    v.y = (unsigned)f2bf(e2) | ((unsigned)f2bf(e3) << 16);               \
                    *(uint2*)(&E[((size_t)grp * NHW + m) * 8 + sub]) = v;                \
                }                                                                        \
            }                                                                            \
        }                                                                                \
    }

    STAGE(0, 0)
    __syncthreads();
    STAGE(1, 1)
    COMPUTE(accA, 0)    // mt 0
    __syncthreads();
    for (int base = 1; base + 1 < 9; base += 2) {
        STAGE(0, base + 1)
        EXPSTORE(accA, base - 1)
        COMPUTE(accB, 1)        // mt = base (odd, buf 1)
        __syncthreads();
        if (base + 2 < 9) STAGE(1, base + 2)
        EXPSTORE(accB, base)
        COMPUTE(accA, 0)        // mt = base+1 (even, buf 0)
        __syncthreads();
    }
    EXPSTORE(accA, 8)
#undef STAGE
#undef COMPUTE
#undef EXPSTORE

#pragma unroll
    for (int i = 0; i < 2; ++i)
#pragma unroll
        for (int r = 0; r < 4; ++r) {
            float v = zacc[i][r];
            v += __shfl_xor(v, 1);
            v += __shfl_xor(v, 2);
            v += __shfl_xor(v, 4);
            v += __shfl_xor(v, 8);
            if (lr == 0) Zpart[(size_t)by * NHW + n0 + i * 16 + lk * 4 + r] = v;
        }
}

// ---------------------------------------------------------------------------
// Merged k_g / k_base.  z=0: G' = (W1@fm)/Z in A-frag-ready layout
// G'[(n>>3)*2048 + o*8 + (n&7)]; z=1: out = W2@ft + b.
// ---------------------------------------------------------------------------
__global__ __launch_bounds__(256) void k_gb(const unsigned short* __restrict__ twb,
                                            const unsigned short* __restrict__ fmT,
                                            const unsigned short* __restrict__ ftT,
                                            const float* __restrict__ Zpart,
                                            const float* __restrict__ tb,
                                            unsigned short* __restrict__ G,
                                            float* __restrict__ out) {
    const int tid = threadIdx.x;
    const int w = tid >> 6, l = tid & 63;
    const int wo = w >> 1, wm = w & 1;
    const int lr = l & 15, lk = l >> 4;
    const int mode = blockIdx.z;
    const int n0 = blockIdx.x * 128, o0 = blockIdx.y * 128;
    const unsigned short* B = mode ? ftT : fmT;
    const int wofs = mode ? 256 : 0;
    f32x4 acc[4][4] = {};
#pragma unroll
    for (int ks = 0; ks < 8; ++ks) {
        const int k = ks * 32 + lk * 8;
        bfrag a[4], b[4];
#pragma unroll
        for (int i = 0; i < 4; ++i)
            a[i] = *(const bfrag*)(twb + (size_t)(o0 + wo * 64 + i * 16 + lr) * 512 + wofs + k);
#pragma unroll
        for (int j = 0; j < 4; ++j)
            b[j] = *(const bfrag*)(B + (size_t)(n0 + wm * 64 + j * 16 + lr) * NCH + k);
#pragma unroll
        for (int i = 0; i < 4; ++i)
#pragma unroll
            for (int j = 0; j < 4; ++j) acc[i][j] = MFMA(a[i], b[j], acc[i][j]);
    }
    if (mode == 0) {
        float zi[4];
#pragma unroll
        for (int j = 0; j < 4; ++j) {
            const int n = n0 + wm * 64 + j * 16 + lr;
            float z = 0.f;
#pragma unroll
            for (int s = 0; s < 16; ++s) z += Zpart[(size_t)s * NHW + n];
            zi[j] = 1.f / z;
        }
#pragma unroll
        for (int i = 0; i < 4; ++i)
#pragma unroll
            for (int j = 0; j < 4; ++j)
#pragma unroll
                for (int r = 0; r < 4; ++r) {
                    const int o = o0 + wo * 64 + i * 16 + lk * 4 + r;
                    const int n = n0 + wm * 64 + j * 16 + lr;
                    G[(size_t)(n >> 3) * 2048 + o * 8 + (n & 7)] = f2bf(acc[i][j][r] * zi[j]);
                }
    } else {
#pragma unroll
        for (int i = 0; i < 4; ++i)
#pragma unroll
            for (int j = 0; j < 4; ++j)
#pragma unroll
                for (int r = 0; r < 4; ++r) {
                    const int o = o0 + wo * 64 + i * 16 + lk * 4 + r;
                    const int m = n0 + wm * 64 + j * 16 + lr;
                    out[(size_t)o * NHW + m] = acc[i][j][r] + tb[o];
                }
    }
}

// ---------------------------------------------------------------------------
// k_apply (r15/r17 structure, twice-validated best): out += G' @ E.
// grid flat 1152: by = id&7 (n-split == XCD), bx = id>>3 (m-tile 64).
// Barrier-free 4-wave streaming; blocks stagger naturally so atomic
// epilogues spread in time (out lines written back once per split).
// 7 structural variants measured worse — this is the balance point.
// ---------------------------------------------------------------------------
__global__ __launch_bounds__(256, 3) void k_apply(const unsigned short* __restrict__ G,
                                                  const unsigned short* __restrict__ E,
                                                  float* __restrict__ out) {
    const int t = threadIdx.x;
    const int w = t >> 6, l = t & 63;
    const int lr = l & 15, lk = l >> 4;
    const int id = blockIdx.x;
    const int by = id & 7;
    const int bx = id >> 3;
    const int m0 = bx * 64;
    const int gbase = by * 144;  // (by*1152)>>3

    f32x4 U[4][4] = {};
    bfrag gaA[4], ebA[4], gaB[4], ebB[4];

#define LOADSET(ga, eb, s)                                                                        \
    {                                                                                             \
        _Pragma("unroll") for (int i = 0; i < 4; ++i)                                             \
            ga[i] = *(const bfrag*)(&G[(size_t)(gbase + (s) * 4 + lk) * 2048 +                    \
                                       (w * 64 + i * 16 + lr) * 8]);                              \
        _Pragma("unroll") for (int j = 0; j < 4; ++j)                                             \
            eb[j] = *(const bfrag*)(&E[((size_t)(gbase + (s) * 4 + lk) * NHW + m0 + j * 16 + lr) * 8]); \
    }
#define MFMASET(ga, eb)                                                                           \
    {                                                                                             \
        __builtin_amdgcn_s_setprio(1);                                                            \
        _Pragma("unroll") for (int i = 0; i < 4; ++i)                                             \
            _Pragma("unroll") for (int j = 0; j < 4; ++j) U[i][j] = MFMA(ga[i], eb[j], U[i][j]);  \
        __builtin_amdgcn_s_setprio(0);                                                            \
    }

    LOADSET(gaA, ebA, 0)
#pragma unroll 2
    for (int s = 0; s < 36; s += 2) {
        LOADSET(gaB, ebB, s + 1)
        MFMASET(gaA, ebA)
        if (s + 2 < 36) LOADSET(gaA, ebA, s + 2)
        MFMASET(gaB, ebB)
    }
#undef LOADSET
#undef MFMASET

#pragma unroll
    for (int i = 0; i < 4; ++i)
#pragma unroll
        for (int j = 0; j < 4; ++j)
#pragma unroll
            for (int r = 0; r < 4; ++r) {
                const int o = w * 64 + i * 16 + lk * 4 + r;
                const int m = m0 + j * 16 + lr;
                atomicAdd(out + (size_t)o * NHW + m, U[i][j][r]);
            }
}

// ---------------------------------------------------------------------------
// Fallback (ws too small for E): r6 k_main — recomputes S. Uses frag-ready G'.
// ---------------------------------------------------------------------------
__global__ __launch_bounds__(256, 2) void k_main(const unsigned short* __restrict__ fmT,
                                                 const unsigned short* __restrict__ ftT,
                                                 const unsigned short* __restrict__ G,
                                                 float* __restrict__ out) {
    __shared__ unsigned short smB[32 * 64 * 8];
    __shared__ unsigned short smE[48 * 64 * 8];
    const int t = threadIdx.x;
    const int w = t >> 6, l = t & 63;
    const int lr = l & 15, lk = l >> 4;
    const int id = blockIdx.x;
    const int by = id & 7;
    const int bx = id >> 3;
    const int m0 = bx * 64;
    const int nbase = by * 1152;

    {
        const int m = t >> 2;
        const int kc0 = t & 3;
#pragma unroll
        for (int p = 0; p < 8; ++p) {
            const int kc = p * 4 + kc0;
            *(bfrag*)(&smB[(kc * 64 + m) * 8]) =
                *(const bfrag*)(ftT + (size_t)(m0 + m) * NCH + kc * 8);
        }
    }
    __syncthreads();

    f32x4 U[4][4] = {};
    for (int c = 0; c < 3; ++c) {
        const int n0 = nbase + c * 384;
        f32x4 acc[6][4] = {};
#pragma unroll
        for (int ks = 0; ks < 8; ++ks) {
            const int k = ks * 32 + lk * 8;
            bfrag a[6], b[4];
#pragma unroll
            for (int i = 0; i < 6; ++i)
                a[i] = *(const bfrag*)(fmT + (size_t)(n0 + w * 96 + i * 16 + lr) * NCH + k);
#pragma unroll
            for (int j = 0; j < 4; ++j)
                b[j] = *(const bfrag*)(&smB[((ks * 4 + lk) * 64 + j * 16 + lr) * 8]);
#pragma unroll
            for (int i = 0; i < 6; ++i)
#pragma unroll
                for (int j = 0; j < 4; ++j) acc[i][j] = MFMA(a[i], b[j], acc[i][j]);
        }
#pragma unroll
        for (int i = 0; i < 6; ++i)
#pragma unroll
            for (int j = 0; j < 4; ++j) {
                const int m = j * 16 + lr;
                const int grp = w * 12 + i * 2 + (lk >> 1);
                uint2 v;
                v.x = (unsigned)f2bf(__expf(acc[i][j][0] * SCALE)) |
                      ((unsigned)f2bf(__expf(acc[i][j][1] * SCALE)) << 16);
                v.y = (unsigned)f2bf(__expf(acc[i][j][2] * SCALE)) |
                      ((unsigned)f2bf(__expf(acc[i][j][3] * SCALE)) << 16);
                *(uint2*)(&smE[(grp * 64 + m) * 8 + (lk & 1) * 4]) = v;
            }
        __syncthreads();
#pragma unroll
        for (int s = 0; s < 12; ++s) {
            bfrag ga[4], eb[4];
#pragma unroll
            for (int i = 0; i < 4; ++i)
                ga[i] = *(const bfrag*)(&G[(size_t)((n0 + s * 32 + lk * 8) >> 3) * 2048 +
                                           (w * 64 + i * 16 + lr) * 8]);
#pragma unroll
            for (int j = 0; j < 4; ++j)
                eb[j] = *(const bfrag*)(&smE[((s * 4 + lk) * 64 + j * 16 + lr) * 8]);
#pragma unroll
            for (int i = 0; i < 4; ++i)
#pragma unroll
                for (int j = 0; j < 4; ++j) U[i][j] = MFMA(ga[i], eb[j], U[i][j]);
        }
        __syncthreads();
    }
#pragma unroll
    for (int i = 0; i < 4; ++i)
#pragma unroll
        for (int j = 0; j < 4; ++j)
#pragma unroll
            for (int r = 0; r < 4; ++r) {
                const int o = w * 64 + i * 16 + lk * 4 + r;
                const int m = m0 + j * 16 + lr;
                atomicAdd(out + (size_t)o * NHW + m, U[i][j][r]);
            }
}

extern "C" void kernel_launch(void* const* d_in, const int* in_sizes, int n_in,
                              void* d_out, int out_size, void* d_ws, size_t ws_size,
                              hipStream_t stream) {
    const float* fm = (const float*)d_in[0];
    const float* ft = (const float*)d_in[1];
    const float* tw = (const float*)d_in[2];
    const float* tb = (const float*)d_in[3];
    float* out = (float*)d_out;

    char* ws = (char*)d_ws;
    float* Zpart = (float*)ws;                                 // 16*9216*4  = 589824
    unsigned short* twb = (unsigned short*)(ws + 589824);      // 256*512*2  = 262144
    unsigned short* fmT = (unsigned short*)(ws + 851968);      // 9216*256*2 = 4718592
    unsigned short* ftT = (unsigned short*)(ws + 5570560);
    unsigned short* G   = (unsigned short*)(ws + 10289152);    // base = 15007744
    unsigned short* E   = (unsigned short*)(ws + 15007744);    // 9216*9216*2
    const size_t needE = 15007744ull + (size_t)NHW * NHW * 2ull;
    const int useE = (ws_size >= needE) ? 1 : 0;

    k_prep<<<dim3(144, 2), 256, 0, stream>>>(fm, ft, fmT, ftT);
    k_prepw<<<dim3(512), 256, 0, stream>>>(tw, twb);
    k_se<<<dim3(1152), 256, 0, stream>>>(fmT, ftT, Zpart, E, useE);
    k_gb<<<dim3(72, 2, 2), 256, 0, stream>>>(twb, fmT, ftT, Zpart, tb, G, out);
    if (useE)
        k_apply<<<dim3(1152), 256, 0, stream>>>(G, E, out);
    else
        k_main<<<dim3(1152), 256, 0, stream>>>(fmT, ftT, G, out);
}